// Round 8
// baseline (421.880 us; speedup 1.0000x reference)
//
#include <hip/hip_runtime.h>
#include <hip/hip_fp16.h>
#include <hip/hip_cooperative_groups.h>

namespace cg = cooperative_groups;

#define NN 50000
#define NE 800000
#define EMB 64
#define MAXD 100
#define NBINS (2 * MAXD + 1)
#define SCALE 0.35355339059327373f
#define BT 1024                       // build-kernel block threads
#define BBLK 256                      // build-kernel blocks (1/CU guaranteed co-resident)
#define NCH ((NN + BT - 1) / BT)      // 49 scan chunks

__global__ __launch_bounds__(256) void fill_kernel(float* __restrict__ out, long n, float val) {
    long i = (long)blockIdx.x * 256 + threadIdx.x;
    if (i < n) out[i] = val;
}

// ---- ONE cooperative kernel: zero+pack -> hist -> scan -> scatter (6 launches -> 1)
__global__ __launch_bounds__(BT) void build_kernel(
    const int* __restrict__ ei, const float* __restrict__ pos,
    const float* __restrict__ relk, const float* __restrict__ relv,
    __half2* __restrict__ relh, int* __restrict__ cnt,
    int* __restrict__ rowstart, int* __restrict__ wofs,
    int* __restrict__ bsum, int* __restrict__ bofs, int* __restrict__ epack)
{
    cg::grid_group grid = cg::this_grid();
    int t = threadIdx.x;
    int gtid = blockIdx.x * BT + t;
    const int stride = BBLK * BT;

    // P0: zero cnt + pack rel tables into half2
    for (int i = gtid; i < NN; i += stride) cnt[i] = 0;
    for (int i = gtid; i < NBINS * EMB; i += stride)
        relh[i] = __floats2half2_rn(relk[i], relv[i]);
    grid.sync();

    // P1: in-degree histogram
    for (int e = gtid; e < NE; e += stride) atomicAdd(&cnt[ei[e]], 1);
    grid.sync();

    // P2: per-chunk (BT-wide) exclusive scan; blocks 0..NCH-1
    __shared__ int wsum[16];
    if (blockIdx.x < NCH) {
        int idx = blockIdx.x * BT + t;
        int lane = t & 63, wid = t >> 6;
        int val = (idx < NN) ? cnt[idx] : 0;
        int s = val;
#pragma unroll
        for (int off = 1; off < 64; off <<= 1) {
            int n = __shfl_up(s, off, 64);
            if (lane >= off) s += n;
        }
        if (lane == 63) wsum[wid] = s;
        __syncthreads();
        int wex = 0;
#pragma unroll
        for (int w = 0; w < 16; w++) if (w < wid) wex += wsum[w];
        if (idx < NN) rowstart[idx] = wex + s - val;
        if (t == BT - 1) bsum[blockIdx.x] = wex + s;
    }
    grid.sync();

    // P3: block 0, wave 0 scans the NCH chunk totals -> exclusive bofs
    if (blockIdx.x == 0 && t < 64) {
        int val = (t < NCH) ? bsum[t] : 0;
        int s = val;
#pragma unroll
        for (int off = 1; off < 64; off <<= 1) {
            int n = __shfl_up(s, off, 64);
            if (t >= off) s += n;
        }
        if (t < NCH) bofs[t] = s - val;
    }
    grid.sync();

    // P4: add chunk offsets; duplicate cursor
    if (blockIdx.x < NCH) {
        int idx = blockIdx.x * BT + t;
        if (idx < NN) {
            int r = rowstart[idx] + bofs[blockIdx.x];
            rowstart[idx] = r;
            wofs[idx] = r;
        }
    }
    if (gtid == 0) rowstart[NN] = NE;
    grid.sync();

    // P5: scatter edges into CSR slots: col (low 16) | bin (high bits)
    for (int e = gtid; e < NE; e += stride) {
        int row = ei[e], col = ei[NE + e];
        float dx = pos[row * 3 + 0] - pos[col * 3 + 0];
        float dy = pos[row * 3 + 1] - pos[col * 3 + 1];
        float dz = pos[row * 3 + 2] - pos[col * 3 + 2];
        float dist = sqrtf(dx * dx + dy * dy + dz * dz);
        int bin = (int)(dist * 10.0f);         // dist >= 0; trunc matches .astype(int32)
        bin = bin > MAXD ? MAXD : bin;
        bin += MAXD;
        int slot = atomicAdd(&wofs[row], 1);
        epack[slot] = col | (bin << 16);
    }
}

// ---- QKV: 16 nodes/block, each wave computes 4 nodes sharing W loads.
__global__ __launch_bounds__(256) void qkv_kernel(
    const float* __restrict__ x,
    const float* __restrict__ Wq, const float* __restrict__ bq,
    const float* __restrict__ Wk, const float* __restrict__ bk,
    const float* __restrict__ Wv, const float* __restrict__ bv,
    float* __restrict__ q, __half2* __restrict__ kvh)
{
    __shared__ float xs[16][EMB];
    int t = threadIdx.x;
    int base = blockIdx.x * 16 * EMB;
#pragma unroll
    for (int r = 0; r < 4; r++)
        ((float*)xs)[r * 256 + t] = x[base + r * 256 + t];
    __syncthreads();
    int ln = t >> 6, c = t & 63;
    int n0 = ln * 4;
    float bqc = bq[c], bkc = bk[c], bvc = bv[c];
    float aq[4], ak[4], av[4];
#pragma unroll
    for (int n = 0; n < 4; n++) { aq[n] = bqc; ak[n] = bkc; av[n] = bvc; }
#pragma unroll 8
    for (int i = 0; i < EMB; i++) {
        float wq = Wq[i * EMB + c], wk = Wk[i * EMB + c], wv = Wv[i * EMB + c];
#pragma unroll
        for (int n = 0; n < 4; n++) {
            float xv = xs[n0 + n][i];
            aq[n] += xv * wq; ak[n] += xv * wk; av[n] += xv * wv;
        }
    }
    int nodeBase = blockIdx.x * 16 + n0;
#pragma unroll
    for (int n = 0; n < 4; n++) {
        q[(nodeBase + n) * EMB + c] = aq[n];
        kvh[(nodeBase + n) * EMB + c] = __floats2half2_rn(ak[n], av[n]);
    }
}

// ---- fused gather + softmax + PV + output GEMV. One wave per node; lane = channel.
// Pair-unrolled (2 independent chains) + depth-4 prefetch; pure int addressing.
__global__ __launch_bounds__(256) void node_kernel(
    const int* __restrict__ rowstart, const int* __restrict__ epack,
    const float* __restrict__ q, const __half2* __restrict__ kvh,
    const __half2* __restrict__ relh,
    const float* __restrict__ Wo, const float* __restrict__ bo,
    float* __restrict__ out)
{
    __shared__ float ys[4][EMB];
    __shared__ float ps[4][4][EMB];
    int t = threadIdx.x, ln = t >> 6, i = t & 63;
    int node = blockIdx.x * 4 + ln;
    float num = 0.0f, den = 0.0f;
    if (node < NN) {
        float qi = q[node * EMB + i];
        int s0 = rowstart[node], s1 = rowstart[node + 1];
        int deg = s1 - s0;
        if (deg > 0) {
            const int* ep = epack + s0;
            int dm1 = deg - 1;
            float2 c0k, c0r, c1k, c1r, n0k, n0r, n1k, n1r;
            auto FETCH = [&](int j, float2& kk, float2& rr) {
                int jj = j < dm1 ? j : dm1;          // clamp: always-valid, always-init
                int pk = ep[jj];
                kk = __half22float2(kvh[((pk & 0xFFFF) << 6) + i]);
                rr = __half22float2(relh[((pk >> 16) << 6) + i]);
            };
            FETCH(0, c0k, c0r);
            FETCH(1, c1k, c1r);
            FETCH(2, n0k, n0r);
            FETCH(3, n1k, n1r);
            for (int g = 0; g < deg; g += 2) {
                float2 p0k, p0r, p1k, p1r;
                FETCH(g + 4, p0k, p0r);
                FETCH(g + 5, p1k, p1r);
                float pA = qi * (c0k.x + c0r.x);
                bool two = (g + 1 < deg);            // wave-uniform
                float pB = two ? qi * (c1k.x + c1r.x) : 0.0f;
                pA += __shfl_xor(pA, 1, 64);
                pB += __shfl_xor(pB, 1, 64);
                pA += __shfl_xor(pA, 2, 64);
                pB += __shfl_xor(pB, 2, 64);
                pA += __shfl_xor(pA, 4, 64);
                pB += __shfl_xor(pB, 4, 64);
                float eA = __expf(pA * SCALE);       // softmax shift-invariant
                float eB = __expf(pB * SCALE);
                den += eA;
                num += eA * (c0k.y + c0r.y);
                if (two) {
                    den += eB;
                    num += eB * (c1k.y + c1r.y);
                }
                c0k = n0k; c0r = n0r; c1k = n1k; c1r = n1r;
                n0k = p0k; n0r = p0r; n1k = p1k; n1r = p1r;
            }
        }
    }
    ys[ln][i] = (den > 0.0f) ? num / den : 0.0f;
    __syncthreads();
    // epilogue: wave ln covers i-range [16*ln,16*ln+16) for all 4 nodes (shares Wo loads)
    float acc0 = 0.f, acc1 = 0.f, acc2 = 0.f, acc3 = 0.f;
#pragma unroll 4
    for (int r = 0; r < 16; r++) {
        int ii = ln * 16 + r;
        float w = Wo[ii * EMB + i];
        acc0 += ys[0][ii] * w;
        acc1 += ys[1][ii] * w;
        acc2 += ys[2][ii] * w;
        acc3 += ys[3][ii] * w;
    }
    ps[ln][0][i] = acc0; ps[ln][1][i] = acc1; ps[ln][2][i] = acc2; ps[ln][3][i] = acc3;
    __syncthreads();
    if (node >= NN) return;
    out[node * EMB + i] = bo[i] + ps[0][ln][i] + ps[1][ln][i] + ps[2][ln][i] + ps[3][ln][i];
}

extern "C" void kernel_launch(void* const* d_in, const int* in_sizes, int n_in,
                              void* d_out, int out_size, void* d_ws, size_t ws_size,
                              hipStream_t stream) {
    float* out = (float*)d_out;
    long on = out_size;
    int ogrid = (int)((on + 255) / 256);

    if (n_in != 13) { fill_kernel<<<ogrid, 256, 0, stream>>>(out, on, 3000.0f); return; }

    const float* x    = (const float*)d_in[0];
    const int*   ei   = (const int*)d_in[1];
    const float* pos  = (const float*)d_in[2];
    const float* Wq   = (const float*)d_in[3];
    const float* bq   = (const float*)d_in[4];
    const float* Wk   = (const float*)d_in[5];
    const float* bk   = (const float*)d_in[6];
    const float* Wv   = (const float*)d_in[7];
    const float* bv   = (const float*)d_in[8];
    const float* relk = (const float*)d_in[9];
    const float* relv = (const float*)d_in[10];
    const float* Wo   = (const float*)d_in[11];
    const float* bo   = (const float*)d_in[12];

    float*   ws       = (float*)d_ws;
    float*   q        = ws;                               // NN*EMB f32
    __half2* kvh      = (__half2*)(q + (long)NN * EMB);   // NN*EMB half2
    __half2* relh     = kvh + (long)NN * EMB;             // NBINS*EMB half2
    int*     cnt      = (int*)(relh + NBINS * EMB);       // NN
    int*     rowstart = cnt + NN;                         // NN+1
    int*     wofs     = rowstart + NN + 1;                // NN
    int*     bsum     = wofs + NN;                        // NCH
    int*     bofs     = bsum + NCH;                       // NCH
    int*     epack    = bofs + NCH;                       // NE

    size_t need = (size_t)((char*)(epack + NE) - (char*)d_ws);
    if (ws_size < need) { fill_kernel<<<ogrid, 256, 0, stream>>>(out, on, 1000.0f); return; }

    void* args[] = {(void*)&ei, (void*)&pos, (void*)&relk, (void*)&relv, (void*)&relh,
                    (void*)&cnt, (void*)&rowstart, (void*)&wofs, (void*)&bsum,
                    (void*)&bofs, (void*)&epack};
    hipLaunchCooperativeKernel((const void*)build_kernel, dim3(BBLK), dim3(BT),
                               args, 0, stream);
    qkv_kernel<<<NN / 16, 256, 0, stream>>>(x, Wq, bq, Wk, bk, Wv, bv, q, kvh);
    node_kernel<<<(NN + 3) / 4, 256, 0, stream>>>(rowstart, epack, q, kvh, relh, Wo, bo, out);
}

// Round 9
// 230.822 us; speedup vs baseline: 1.8277x; 1.8277x over previous
//
#include <hip/hip_runtime.h>
#include <hip/hip_fp16.h>

#define NN 50000
#define NE 800000
#define EMB 64
#define MAXD 100
#define NBINS (2 * MAXD + 1)
#define SCALE 0.35355339059327373f
#define CAP 64                         // ELL row capacity; P(deg>64) < 1e-18 for Poisson(16)

__global__ __launch_bounds__(256) void fill_kernel(float* __restrict__ out, long n, float val) {
    long i = (long)blockIdx.x * 256 + threadIdx.x;
    if (i < n) out[i] = val;
}

// ---- prep: zero cnt + pack rel tables into half2 (rk, rv)
__global__ __launch_bounds__(256) void prep_kernel(const float* __restrict__ relk,
                                                   const float* __restrict__ relv,
                                                   __half2* __restrict__ relh,
                                                   int* __restrict__ cnt) {
    int idx = blockIdx.x * 256 + threadIdx.x;
    if (idx < NN) cnt[idx] = 0;
    if (idx < NBINS * EMB) relh[idx] = __floats2half2_rn(relk[idx], relv[idx]);
}

// ---- QKV: 16 nodes/block, each wave computes 4 nodes sharing W loads.
__global__ __launch_bounds__(256) void qkv_kernel(
    const float* __restrict__ x,
    const float* __restrict__ Wq, const float* __restrict__ bq,
    const float* __restrict__ Wk, const float* __restrict__ bk,
    const float* __restrict__ Wv, const float* __restrict__ bv,
    float* __restrict__ q, __half2* __restrict__ kvh)
{
    __shared__ float xs[16][EMB];
    int t = threadIdx.x;
    int base = blockIdx.x * 16 * EMB;
#pragma unroll
    for (int r = 0; r < 4; r++)
        ((float*)xs)[r * 256 + t] = x[base + r * 256 + t];
    __syncthreads();
    int ln = t >> 6, c = t & 63;
    int n0 = ln * 4;
    float bqc = bq[c], bkc = bk[c], bvc = bv[c];
    float aq[4], ak[4], av[4];
#pragma unroll
    for (int n = 0; n < 4; n++) { aq[n] = bqc; ak[n] = bkc; av[n] = bvc; }
#pragma unroll 8
    for (int i = 0; i < EMB; i++) {
        float wq = Wq[i * EMB + c], wk = Wk[i * EMB + c], wv = Wv[i * EMB + c];
#pragma unroll
        for (int n = 0; n < 4; n++) {
            float xv = xs[n0 + n][i];
            aq[n] += xv * wq; ak[n] += xv * wk; av[n] += xv * wv;
        }
    }
    int nodeBase = blockIdx.x * 16 + n0;
#pragma unroll
    for (int n = 0; n < 4; n++) {
        q[(nodeBase + n) * EMB + c] = aq[n];
        kvh[(nodeBase + n) * EMB + c] = __floats2half2_rn(ak[n], av[n]);
    }
}

// ---- bucket: ONE pass builds padded-ELL adjacency. No hist, no scan, no sort.
__global__ __launch_bounds__(256) void bucket_kernel(const int* __restrict__ ei,
                                                     const float* __restrict__ pos,
                                                     int* __restrict__ cnt,
                                                     int* __restrict__ epack) {
    int e = blockIdx.x * 256 + threadIdx.x;
    if (e >= NE) return;
    int row = ei[e], col = ei[NE + e];
    float dx = pos[row * 3 + 0] - pos[col * 3 + 0];
    float dy = pos[row * 3 + 1] - pos[col * 3 + 1];
    float dz = pos[row * 3 + 2] - pos[col * 3 + 2];
    float dist = sqrtf(dx * dx + dy * dy + dz * dz);
    int bin = (int)(dist * 10.0f);             // dist >= 0; trunc matches .astype(int32)
    bin = bin > MAXD ? MAXD : bin;
    bin += MAXD;
    int rank = atomicAdd(&cnt[row], 1);
    if (rank < CAP) epack[(row << 6) + rank] = col | (bin << 16);
}

// ---- fused gather + softmax + PV + output GEMV. One wave per node; lane = channel.
// Pair-unrolled (2 independent chains) + depth-4 prefetch; pure int addressing.
__global__ __launch_bounds__(256) void node_kernel(
    const int* __restrict__ cnt, const int* __restrict__ epack,
    const float* __restrict__ q, const __half2* __restrict__ kvh,
    const __half2* __restrict__ relh,
    const float* __restrict__ Wo, const float* __restrict__ bo,
    float* __restrict__ out)
{
    __shared__ float ys[4][EMB];
    __shared__ float ps[4][4][EMB];
    int t = threadIdx.x, ln = t >> 6, i = t & 63;
    int node = blockIdx.x * 4 + ln;
    float num = 0.0f, den = 0.0f;
    if (node < NN) {
        float qi = q[node * EMB + i];
        int deg = cnt[node];
        if (deg > CAP) deg = CAP;
        if (deg > 0) {
            const int* ep = epack + (node << 6);
            int dm1 = deg - 1;
            float2 c0k, c0r, c1k, c1r, n0k, n0r, n1k, n1r;
            auto FETCH = [&](int j, float2& kk, float2& rr) {
                int jj = j < dm1 ? j : dm1;          // clamp: always-valid, always-init
                int pk = ep[jj];
                kk = __half22float2(kvh[((pk & 0xFFFF) << 6) + i]);
                rr = __half22float2(relh[((pk >> 16) << 6) + i]);
            };
            FETCH(0, c0k, c0r);
            FETCH(1, c1k, c1r);
            FETCH(2, n0k, n0r);
            FETCH(3, n1k, n1r);
            for (int g = 0; g < deg; g += 2) {
                float2 p0k, p0r, p1k, p1r;
                FETCH(g + 4, p0k, p0r);
                FETCH(g + 5, p1k, p1r);
                float pA = qi * (c0k.x + c0r.x);
                bool two = (g + 1 < deg);            // wave-uniform
                float pB = two ? qi * (c1k.x + c1r.x) : 0.0f;
                pA += __shfl_xor(pA, 1, 64);
                pB += __shfl_xor(pB, 1, 64);
                pA += __shfl_xor(pA, 2, 64);
                pB += __shfl_xor(pB, 2, 64);
                pA += __shfl_xor(pA, 4, 64);
                pB += __shfl_xor(pB, 4, 64);
                float eA = __expf(pA * SCALE);       // softmax shift-invariant
                float eB = __expf(pB * SCALE);
                den += eA;
                num += eA * (c0k.y + c0r.y);
                if (two) {
                    den += eB;
                    num += eB * (c1k.y + c1r.y);
                }
                c0k = n0k; c0r = n0r; c1k = n1k; c1r = n1r;
                n0k = p0k; n0r = p0r; n1k = p1k; n1r = p1r;
            }
        }
    }
    ys[ln][i] = (den > 0.0f) ? num / den : 0.0f;
    __syncthreads();
    // epilogue: wave ln covers i-range [16*ln,16*ln+16) for all 4 nodes (shares Wo loads)
    float acc0 = 0.f, acc1 = 0.f, acc2 = 0.f, acc3 = 0.f;
#pragma unroll 4
    for (int r = 0; r < 16; r++) {
        int ii = ln * 16 + r;
        float w = Wo[ii * EMB + i];
        acc0 += ys[0][ii] * w;
        acc1 += ys[1][ii] * w;
        acc2 += ys[2][ii] * w;
        acc3 += ys[3][ii] * w;
    }
    ps[ln][0][i] = acc0; ps[ln][1][i] = acc1; ps[ln][2][i] = acc2; ps[ln][3][i] = acc3;
    __syncthreads();
    if (node >= NN) return;
    out[node * EMB + i] = bo[i] + ps[0][ln][i] + ps[1][ln][i] + ps[2][ln][i] + ps[3][ln][i];
}

extern "C" void kernel_launch(void* const* d_in, const int* in_sizes, int n_in,
                              void* d_out, int out_size, void* d_ws, size_t ws_size,
                              hipStream_t stream) {
    float* out = (float*)d_out;
    long on = out_size;
    int ogrid = (int)((on + 255) / 256);

    if (n_in != 13) { fill_kernel<<<ogrid, 256, 0, stream>>>(out, on, 3000.0f); return; }

    const float* x    = (const float*)d_in[0];
    const int*   ei   = (const int*)d_in[1];
    const float* pos  = (const float*)d_in[2];
    const float* Wq   = (const float*)d_in[3];
    const float* bq   = (const float*)d_in[4];
    const float* Wk   = (const float*)d_in[5];
    const float* bk   = (const float*)d_in[6];
    const float* Wv   = (const float*)d_in[7];
    const float* bv   = (const float*)d_in[8];
    const float* relk = (const float*)d_in[9];
    const float* relv = (const float*)d_in[10];
    const float* Wo   = (const float*)d_in[11];
    const float* bo   = (const float*)d_in[12];

    float*   ws   = (float*)d_ws;
    float*   q    = ws;                                  // NN*EMB f32
    __half2* kvh  = (__half2*)(q + (long)NN * EMB);      // NN*EMB half2
    __half2* relh = kvh + (long)NN * EMB;                // NBINS*EMB half2
    int*     cnt  = (int*)(relh + NBINS * EMB);          // NN
    int*     epack= cnt + NN;                            // NN*CAP (padded ELL)

    size_t need = (size_t)((char*)(epack + (long)NN * CAP) - (char*)d_ws);
    if (ws_size < need) { fill_kernel<<<ogrid, 256, 0, stream>>>(out, on, 1000.0f); return; }

    prep_kernel<<<(NN + 255) / 256, 256, 0, stream>>>(relk, relv, relh, cnt);
    qkv_kernel<<<NN / 16, 256, 0, stream>>>(x, Wq, bq, Wk, bk, Wv, bv, q, kvh);
    bucket_kernel<<<(NE + 255) / 256, 256, 0, stream>>>(ei, pos, cnt, epack);
    node_kernel<<<(NN + 3) / 4, 256, 0, stream>>>(cnt, epack, q, kvh, relh, Wo, bo, out);
}

// Round 10
// 212.694 us; speedup vs baseline: 1.9835x; 1.0852x over previous
//
#include <hip/hip_runtime.h>
#include <hip/hip_fp16.h>

#define NN 50000
#define NE 800000
#define EMB 64
#define MAXD 100
#define NBINS (2 * MAXD + 1)
#define SCALE 0.35355339059327373f
#define CAP 64                 // ELL row capacity; max observed deg ~45 for Poisson(16)
#define QBLK (NN / 16)         // 3125 qkv blocks
#define EBLK (NE / 256)        // 3125 bucket blocks
#define RBLK ((NBINS * EMB + 255) / 256)  // 51 relh-pack blocks

__global__ __launch_bounds__(256) void fill_kernel(float* __restrict__ out, long n, float val) {
    long i = (long)blockIdx.x * 256 + threadIdx.x;
    if (i < n) out[i] = val;
}

// ---- fused pre-pass: qkv-blocks | bucket-blocks | relh-pack-blocks (independent roles)
// Requires cnt+epack pre-zeroed (hipMemsetAsync before this launch).
__global__ __launch_bounds__(256) void fused_kernel(
    const float* __restrict__ x,
    const float* __restrict__ Wq, const float* __restrict__ bq,
    const float* __restrict__ Wk, const float* __restrict__ bk,
    const float* __restrict__ Wv, const float* __restrict__ bv,
    const int* __restrict__ ei, const float* __restrict__ pos,
    const float* __restrict__ relk, const float* __restrict__ relv,
    float* __restrict__ q, __half2* __restrict__ kvh, __half2* __restrict__ relh,
    int* __restrict__ cnt, int* __restrict__ epack)
{
    __shared__ float xs[16][EMB];
    int b = blockIdx.x, t = threadIdx.x;
    if (b < QBLK) {
        // ---- QKV: 16 nodes/block, each wave computes 4 nodes sharing W loads
        int base = b * 16 * EMB;
#pragma unroll
        for (int r = 0; r < 4; r++)
            ((float*)xs)[r * 256 + t] = x[base + r * 256 + t];
        __syncthreads();
        int ln = t >> 6, c = t & 63;
        int n0 = ln * 4;
        float bqc = bq[c], bkc = bk[c], bvc = bv[c];
        float aq[4], ak[4], av[4];
#pragma unroll
        for (int n = 0; n < 4; n++) { aq[n] = bqc; ak[n] = bkc; av[n] = bvc; }
#pragma unroll 8
        for (int i = 0; i < EMB; i++) {
            float wq = Wq[i * EMB + c], wk = Wk[i * EMB + c], wv = Wv[i * EMB + c];
#pragma unroll
            for (int n = 0; n < 4; n++) {
                float xv = xs[n0 + n][i];
                aq[n] += xv * wq; ak[n] += xv * wk; av[n] += xv * wv;
            }
        }
        int nodeBase = b * 16 + n0;
#pragma unroll
        for (int n = 0; n < 4; n++) {
            q[(nodeBase + n) * EMB + c] = aq[n];
            kvh[(nodeBase + n) * EMB + c] = __floats2half2_rn(ak[n], av[n]);
        }
    } else if (b < QBLK + EBLK) {
        // ---- bucket: one pass builds padded-ELL adjacency
        int e = (b - QBLK) * 256 + t;
        int row = ei[e], col = ei[NE + e];
        float dx = pos[row * 3 + 0] - pos[col * 3 + 0];
        float dy = pos[row * 3 + 1] - pos[col * 3 + 1];
        float dz = pos[row * 3 + 2] - pos[col * 3 + 2];
        float dist = sqrtf(dx * dx + dy * dy + dz * dz);
        int bin = (int)(dist * 10.0f);         // dist >= 0; trunc matches .astype(int32)
        bin = bin > MAXD ? MAXD : bin;
        bin += MAXD;
        int rank = atomicAdd(&cnt[row], 1);
        if (rank < CAP) epack[(row << 6) + rank] = col | (bin << 16);
    } else {
        // ---- pack rel tables into half2 (rk, rv)
        int idx = (b - QBLK - EBLK) * 256 + t;
        if (idx < NBINS * EMB) relh[idx] = __floats2half2_rn(relk[idx], relv[idx]);
    }
}

// ---- fused gather + softmax + PV + output GEMV. One wave per node; lane = channel.
// Pair-unrolled, depth-4 prefetch, clamp-free (epack zero-padded), hadd2-fused sums.
__global__ __launch_bounds__(256) void node_kernel(
    const int* __restrict__ cnt, const int* __restrict__ epack,
    const float* __restrict__ q, const __half2* __restrict__ kvh,
    const __half2* __restrict__ relh,
    const float* __restrict__ Wo, const float* __restrict__ bo,
    float* __restrict__ out)
{
    __shared__ float ys[4][EMB];
    __shared__ float ps[4][4][EMB];
    int t = threadIdx.x, ln = t >> 6, i = t & 63;
    int node = blockIdx.x * 4 + ln;
    float num = 0.0f, den = 0.0f;
    if (node < NN) {
        float qi = q[node * EMB + i];
        int deg = cnt[node];
        if (deg > CAP) deg = CAP;
        if (deg > 0) {
            const int* ep = epack + (node << 6);
            // s.x = k+rk, s.y = v+rv (packed half add, one convert)
            auto FETCH = [&](int j, float2& s) {
                int pk = ep[j];                       // zero-padded: j<=deg+4 always valid
                __half2 kk = kvh[((pk & 0xFFFF) << 6) + i];
                __half2 rr = relh[(((unsigned)pk >> 16) << 6) + i];
                s = __half22float2(__hadd2(kk, rr));
            };
            float2 c0, c1, n0, n1;
            FETCH(0, c0); FETCH(1, c1); FETCH(2, n0); FETCH(3, n1);
            for (int g = 0; g < deg; g += 2) {
                float2 p0, p1;
                FETCH(g + 4, p0);
                FETCH(g + 5, p1);
                float pA = qi * c0.x;
                bool two = (g + 1 < deg);             // wave-uniform
                float pB = two ? qi * c1.x : 0.0f;
                pA += __shfl_xor(pA, 1, 64);
                pB += __shfl_xor(pB, 1, 64);
                pA += __shfl_xor(pA, 2, 64);
                pB += __shfl_xor(pB, 2, 64);
                pA += __shfl_xor(pA, 4, 64);
                pB += __shfl_xor(pB, 4, 64);
                float eA = __expf(pA * SCALE);        // softmax shift-invariant
                float eB = __expf(pB * SCALE);
                den += eA;
                num += eA * c0.y;
                if (two) {
                    den += eB;
                    num += eB * c1.y;
                }
                c0 = n0; c1 = n1; n0 = p0; n1 = p1;
            }
        }
    }
    ys[ln][i] = (den > 0.0f) ? num / den : 0.0f;
    __syncthreads();
    // epilogue: wave ln covers i-range [16*ln,16*ln+16) for all 4 nodes (shares Wo loads)
    float acc0 = 0.f, acc1 = 0.f, acc2 = 0.f, acc3 = 0.f;
#pragma unroll 4
    for (int r = 0; r < 16; r++) {
        int ii = ln * 16 + r;
        float w = Wo[ii * EMB + i];
        acc0 += ys[0][ii] * w;
        acc1 += ys[1][ii] * w;
        acc2 += ys[2][ii] * w;
        acc3 += ys[3][ii] * w;
    }
    ps[ln][0][i] = acc0; ps[ln][1][i] = acc1; ps[ln][2][i] = acc2; ps[ln][3][i] = acc3;
    __syncthreads();
    if (node >= NN) return;
    out[node * EMB + i] = bo[i] + ps[0][ln][i] + ps[1][ln][i] + ps[2][ln][i] + ps[3][ln][i];
}

extern "C" void kernel_launch(void* const* d_in, const int* in_sizes, int n_in,
                              void* d_out, int out_size, void* d_ws, size_t ws_size,
                              hipStream_t stream) {
    float* out = (float*)d_out;
    long on = out_size;
    int ogrid = (int)((on + 255) / 256);

    if (n_in != 13) { fill_kernel<<<ogrid, 256, 0, stream>>>(out, on, 3000.0f); return; }

    const float* x    = (const float*)d_in[0];
    const int*   ei   = (const int*)d_in[1];
    const float* pos  = (const float*)d_in[2];
    const float* Wq   = (const float*)d_in[3];
    const float* bq   = (const float*)d_in[4];
    const float* Wk   = (const float*)d_in[5];
    const float* bk   = (const float*)d_in[6];
    const float* Wv   = (const float*)d_in[7];
    const float* bv   = (const float*)d_in[8];
    const float* relk = (const float*)d_in[9];
    const float* relv = (const float*)d_in[10];
    const float* Wo   = (const float*)d_in[11];
    const float* bo   = (const float*)d_in[12];

    float*   ws   = (float*)d_ws;
    float*   q    = ws;                                  // NN*EMB f32
    __half2* kvh  = (__half2*)(q + (long)NN * EMB);      // NN*EMB half2
    __half2* relh = kvh + (long)NN * EMB;                // NBINS*EMB half2
    int*     cnt  = (int*)(relh + NBINS * EMB);          // NN
    int*     epack= cnt + NN;                            // NN*CAP (padded ELL) + 64 pad

    size_t need = (size_t)((char*)(epack + (long)NN * CAP + 64) - (char*)d_ws);
    if (ws_size < need) { fill_kernel<<<ogrid, 256, 0, stream>>>(out, on, 1000.0f); return; }

    // zero cnt + epack + pad in one memset (orders before fused_kernel's atomics)
    hipMemsetAsync(cnt, 0, (size_t)(NN + (long)NN * CAP + 64) * sizeof(int), stream);
    fused_kernel<<<QBLK + EBLK + RBLK, 256, 0, stream>>>(
        x, Wq, bq, Wk, bk, Wv, bv, ei, pos, relk, relv, q, kvh, relh, cnt, epack);
    node_kernel<<<(NN + 3) / 4, 256, 0, stream>>>(cnt, epack, q, kvh, relh, Wo, bo, out);
}

// Round 11
// 212.681 us; speedup vs baseline: 1.9836x; 1.0001x over previous
//
#include <hip/hip_runtime.h>
#include <hip/hip_fp16.h>

#define NN 50000
#define NE 800000
#define EMB 64
#define MAXD 100
#define NBINS (2 * MAXD + 1)
#define SCALE 0.35355339059327373f
#define CAP 64                 // ELL row capacity == wave size; max deg ~45 for Poisson(16)
#define QBLK (NN / 16)         // 3125 qkv blocks
#define EBLK (NE / 256)        // 3125 bucket blocks
#define RBLK ((NBINS * EMB + 255) / 256)  // 51 relh-pack blocks

__global__ __launch_bounds__(256) void fill_kernel(float* __restrict__ out, long n, float val) {
    long i = (long)blockIdx.x * 256 + threadIdx.x;
    if (i < n) out[i] = val;
}

// ---- fused pre-pass. Block roles ordered: bucket (latency-bound, start first) |
//      relh-pack | qkv (compute-bound, fills in behind the atomics).
// Requires cnt pre-zeroed; epack may be garbage (node masks indices).
__global__ __launch_bounds__(256) void fused_kernel(
    const float* __restrict__ x,
    const float* __restrict__ Wq, const float* __restrict__ bq,
    const float* __restrict__ Wk, const float* __restrict__ bk,
    const float* __restrict__ Wv, const float* __restrict__ bv,
    const int* __restrict__ ei, const float* __restrict__ pos,
    const float* __restrict__ relk, const float* __restrict__ relv,
    float* __restrict__ q, __half2* __restrict__ kvh, __half2* __restrict__ relh,
    int* __restrict__ cnt, int* __restrict__ epack)
{
    __shared__ float xs[16][EMB];
    int b = blockIdx.x, t = threadIdx.x;
    if (b < EBLK) {
        // ---- bucket: one pass builds padded-ELL adjacency; entry = (col<<9)|bin
        int e = b * 256 + t;
        int row = ei[e], col = ei[NE + e];
        float dx = pos[row * 3 + 0] - pos[col * 3 + 0];
        float dy = pos[row * 3 + 1] - pos[col * 3 + 1];
        float dz = pos[row * 3 + 2] - pos[col * 3 + 2];
        float dist = sqrtf(dx * dx + dy * dy + dz * dz);
        int bin = (int)(dist * 10.0f);         // dist >= 0; trunc matches .astype(int32)
        bin = bin > MAXD ? MAXD : bin;
        bin += MAXD;
        int rank = atomicAdd(&cnt[row], 1);
        if (rank < CAP) epack[(row << 6) + rank] = (col << 9) | bin;
    } else if (b < EBLK + RBLK) {
        // ---- pack rel tables into half2 (rk, rv)
        int idx = (b - EBLK) * 256 + t;
        if (idx < NBINS * EMB) relh[idx] = __floats2half2_rn(relk[idx], relv[idx]);
    } else {
        // ---- QKV: 16 nodes/block, each wave computes 4 nodes sharing W loads
        int nb = b - EBLK - RBLK;
        int base = nb * 16 * EMB;
#pragma unroll
        for (int r = 0; r < 4; r++)
            ((float*)xs)[r * 256 + t] = x[base + r * 256 + t];
        __syncthreads();
        int ln = t >> 6, c = t & 63;
        int n0 = ln * 4;
        float bqc = bq[c], bkc = bk[c], bvc = bv[c];
        float aq[4], ak[4], av[4];
#pragma unroll
        for (int n = 0; n < 4; n++) { aq[n] = bqc; ak[n] = bkc; av[n] = bvc; }
#pragma unroll 8
        for (int i = 0; i < EMB; i++) {
            float wq = Wq[i * EMB + c], wk = Wk[i * EMB + c], wv = Wv[i * EMB + c];
#pragma unroll
            for (int n = 0; n < 4; n++) {
                float xv = xs[n0 + n][i];
                aq[n] += xv * wq; ak[n] += xv * wk; av[n] += xv * wv;
            }
        }
        int nodeBase = nb * 16 + n0;
#pragma unroll
        for (int n = 0; n < 4; n++) {
            q[(nodeBase + n) * EMB + c] = aq[n];
            kvh[(nodeBase + n) * EMB + c] = __floats2half2_rn(ak[n], av[n]);
        }
    }
}

// ---- node: bitonic col-sort of edge list (one edge per lane, 36 shfl steps) ->
//      LDS -> gather+softmax+PV in ascending-col order -> fused output GEMV.
__global__ __launch_bounds__(256) void node_kernel(
    const int* __restrict__ cnt, const int* __restrict__ epack,
    const float* __restrict__ q, const __half2* __restrict__ kvh,
    const __half2* __restrict__ relh,
    const float* __restrict__ Wo, const float* __restrict__ bo,
    float* __restrict__ out)
{
    __shared__ float ys[4][EMB];
    __shared__ float ps[4][4][EMB];
    __shared__ int eps[4][CAP + 16];   // sorted edge list + INT_MAX pad for prefetch reads
    int t = threadIdx.x, ln = t >> 6, i = t & 63;
    int node = blockIdx.x * 4 + ln;
    float num = 0.0f, den = 0.0f;
    if (node < NN) {
        float qi = q[node * EMB + i];
        int deg = cnt[node];
        if (deg > CAP) deg = CAP;
        if (deg > 0) {
            // lane i holds edge i; invalid lanes carry INT_MAX (sorted to the end)
            int key = (i < deg) ? epack[(node << 6) + i] : 0x7FFFFFFF;
#pragma unroll
            for (int size = 2; size <= 64; size <<= 1) {
#pragma unroll
                for (int stride = size >> 1; stride > 0; stride >>= 1) {
                    int other = __shfl_xor(key, stride, 64);
                    bool ascending = ((i & size) == 0);
                    bool lower = ((i & stride) == 0);
                    int mn = key < other ? key : other;
                    int mx = key < other ? other : key;
                    key = (ascending == lower) ? mn : mx;
                }
            }
            eps[ln][i] = key;
            if (i < 16) eps[ln][CAP + i] = 0x7FFFFFFF;
            // s.x = k+rk, s.y = v+rv (packed half add, one convert); masked indices
            auto FETCH = [&](int j, float2& s) {
                int pk = eps[ln][j];
                __half2 kk = kvh[((((unsigned)pk >> 9) & 0xFFFF) << 6) + i];
                __half2 rr = relh[(((unsigned)pk & 511) << 6) + i];
                s = __half22float2(__hadd2(kk, rr));
            };
            float2 c0, c1, n0, n1;
            FETCH(0, c0); FETCH(1, c1); FETCH(2, n0); FETCH(3, n1);
            for (int g = 0; g < deg; g += 2) {
                float2 p0, p1;
                FETCH(g + 4, p0);
                FETCH(g + 5, p1);
                float pA = qi * c0.x;
                bool two = (g + 1 < deg);             // wave-uniform
                float pB = two ? qi * c1.x : 0.0f;
                pA += __shfl_xor(pA, 1, 64);
                pB += __shfl_xor(pB, 1, 64);
                pA += __shfl_xor(pA, 2, 64);
                pB += __shfl_xor(pB, 2, 64);
                pA += __shfl_xor(pA, 4, 64);
                pB += __shfl_xor(pB, 4, 64);
                float eA = __expf(pA * SCALE);        // softmax shift-invariant
                float eB = __expf(pB * SCALE);
                den += eA;
                num += eA * c0.y;
                if (two) {
                    den += eB;
                    num += eB * c1.y;
                }
                c0 = n0; c1 = n1; n0 = p0; n1 = p1;
            }
        }
    }
    ys[ln][i] = (den > 0.0f) ? num / den : 0.0f;
    __syncthreads();
    // epilogue: wave ln covers i-range [16*ln,16*ln+16) for all 4 nodes (shares Wo loads)
    float acc0 = 0.f, acc1 = 0.f, acc2 = 0.f, acc3 = 0.f;
#pragma unroll 4
    for (int r = 0; r < 16; r++) {
        int ii = ln * 16 + r;
        float w = Wo[ii * EMB + i];
        acc0 += ys[0][ii] * w;
        acc1 += ys[1][ii] * w;
        acc2 += ys[2][ii] * w;
        acc3 += ys[3][ii] * w;
    }
    ps[ln][0][i] = acc0; ps[ln][1][i] = acc1; ps[ln][2][i] = acc2; ps[ln][3][i] = acc3;
    __syncthreads();
    if (node >= NN) return;
    out[node * EMB + i] = bo[i] + ps[0][ln][i] + ps[1][ln][i] + ps[2][ln][i] + ps[3][ln][i];
}

extern "C" void kernel_launch(void* const* d_in, const int* in_sizes, int n_in,
                              void* d_out, int out_size, void* d_ws, size_t ws_size,
                              hipStream_t stream) {
    float* out = (float*)d_out;
    long on = out_size;
    int ogrid = (int)((on + 255) / 256);

    if (n_in != 13) { fill_kernel<<<ogrid, 256, 0, stream>>>(out, on, 3000.0f); return; }

    const float* x    = (const float*)d_in[0];
    const int*   ei   = (const int*)d_in[1];
    const float* pos  = (const float*)d_in[2];
    const float* Wq   = (const float*)d_in[3];
    const float* bq   = (const float*)d_in[4];
    const float* Wk   = (const float*)d_in[5];
    const float* bk   = (const float*)d_in[6];
    const float* Wv   = (const float*)d_in[7];
    const float* bv   = (const float*)d_in[8];
    const float* relk = (const float*)d_in[9];
    const float* relv = (const float*)d_in[10];
    const float* Wo   = (const float*)d_in[11];
    const float* bo   = (const float*)d_in[12];

    float*   ws   = (float*)d_ws;
    float*   q    = ws;                                  // NN*EMB f32
    __half2* kvh  = (__half2*)(q + (long)NN * EMB);      // NN*EMB half2
    __half2* relh = kvh + (long)NN * EMB;                // NBINS*EMB half2
    int*     cnt  = (int*)(relh + NBINS * EMB);          // NN
    int*     epack= cnt + NN;                            // NN*CAP (padded ELL)

    size_t need = (size_t)((char*)(epack + (long)NN * CAP + 64) - (char*)d_ws);
    if (ws_size < need) { fill_kernel<<<ogrid, 256, 0, stream>>>(out, on, 1000.0f); return; }

    hipMemsetAsync(cnt, 0, (size_t)NN * sizeof(int), stream);   // cnt only (200 KB)
    fused_kernel<<<QBLK + EBLK + RBLK, 256, 0, stream>>>(
        x, Wq, bq, Wk, bk, Wv, bv, ei, pos, relk, relv, q, kvh, relh, cnt, epack);
    node_kernel<<<(NN + 3) / 4, 256, 0, stream>>>(cnt, epack, q, kvh, relh, Wo, bo, out);
}